// Round 1
// baseline (96.491 us; speedup 1.0000x reference)
//
#include <hip/hip_runtime.h>
#include <hip/hip_bf16.h>

// One 16-lane group per segment. Segment boundaries via binary search on the
// sorted seg[] array (seg = repeat(arange(B), lens), lens >= 1).
__global__ void seg_mean_kernel(const int* __restrict__ idx,
                                const int* __restrict__ seg,
                                int n_elem,
                                const int* __restrict__ user_id,
                                const float* __restrict__ ufac,
                                const float* __restrict__ efac,
                                float* __restrict__ out,   // out[b] = mean dot
                                int B)
{
    int gid = blockIdx.x * blockDim.x + threadIdx.x;
    int group = gid >> 4;      // 16 lanes per segment
    int lane = gid & 15;
    if (group >= B) return;
    const int b = group;

    // lower_bound(seg, b) and lower_bound(seg, b+1) — all 16 lanes redundantly
    int lo = 0, hi = n_elem;
    while (lo < hi) { int mid = (lo + hi) >> 1; if (seg[mid] < b) lo = mid + 1; else hi = mid; }
    const int start = lo;
    hi = n_elem;
    while (lo < hi) { int mid = (lo + hi) >> 1; if (seg[mid] < b + 1) lo = mid + 1; else hi = mid; }
    const int end = lo;

    const int uid = user_id[b];
    const float4 uv = *reinterpret_cast<const float4*>(ufac + (size_t)uid * 64 + lane * 4);

    float acc = 0.0f;
    for (int e = start; e < end; ++e) {
        const int ei = idx[e];
        const float4 ev = *reinterpret_cast<const float4*>(efac + (size_t)ei * 64 + lane * 4);
        acc += ev.x * uv.x + ev.y * uv.y + ev.z * uv.z + ev.w * uv.w;
    }

    // reduce across the 16-lane group (stays inside group for masks 1,2,4,8)
    acc += __shfl_xor(acc, 1, 64);
    acc += __shfl_xor(acc, 2, 64);
    acc += __shfl_xor(acc, 4, 64);
    acc += __shfl_xor(acc, 8, 64);

    if (lane == 0) {
        const float cnt = (float)(end - start);
        out[b] = acc / fmaxf(cnt, 1.0f);
    }
}

// Per-row finalize: scores = softmax(leaky_relu(u @ K, 0.2)), prediction =
// weighted mean of ca/cd/cg (already in d_out).
__global__ void finalize_kernel(const int* __restrict__ user_id,
                                const float* __restrict__ ufac,
                                const float* __restrict__ relk,  // (64,3) row-major
                                float* __restrict__ out,
                                int B)
{
    int b = blockIdx.x * blockDim.x + threadIdx.x;
    if (b >= B) return;

    const float* u = ufac + (size_t)user_id[b] * 64;
    float s0 = 0.f, s1 = 0.f, s2 = 0.f;
#pragma unroll 8
    for (int d = 0; d < 64; ++d) {
        const float uv = u[d];
        s0 += uv * relk[d * 3 + 0];
        s1 += uv * relk[d * 3 + 1];
        s2 += uv * relk[d * 3 + 2];
    }
    // leaky_relu(x, 0.2)
    s0 = s0 > 0.f ? s0 : 0.2f * s0;
    s1 = s1 > 0.f ? s1 : 0.2f * s1;
    s2 = s2 > 0.f ? s2 : 0.2f * s2;
    // softmax over 3
    const float m = fmaxf(s0, fmaxf(s1, s2));
    const float e0 = expf(s0 - m), e1 = expf(s1 - m), e2 = expf(s2 - m);
    const float inv = 1.0f / (e0 + e1 + e2);
    const float p0 = e0 * inv, p1 = e1 * inv, p2 = e2 * inv;

    const float ca = out[(size_t)4 * B + b];
    const float cd = out[(size_t)5 * B + b];
    const float cg = out[(size_t)6 * B + b];
    const float pred = (ca * p0 + cd * p1 + cg * p2) / (p0 + p1 + p2);

    out[b] = pred;
    out[(size_t)B + 3 * b + 0] = p0;
    out[(size_t)B + 3 * b + 1] = p1;
    out[(size_t)B + 3 * b + 2] = p2;
}

extern "C" void kernel_launch(void* const* d_in, const int* in_sizes, int n_in,
                              void* d_out, int out_size, void* d_ws, size_t ws_size,
                              hipStream_t stream) {
    const int*   user_id = (const int*)  d_in[0];
    const int*   a_idx   = (const int*)  d_in[1];
    const int*   a_seg   = (const int*)  d_in[2];
    const int*   dd_idx  = (const int*)  d_in[3];
    const int*   dd_seg  = (const int*)  d_in[4];
    const int*   g_idx   = (const int*)  d_in[5];
    const int*   g_seg   = (const int*)  d_in[6];
    const float* ufac    = (const float*)d_in[7];
    const float* efac    = (const float*)d_in[8];
    const float* relk    = (const float*)d_in[9];
    float* out = (float*)d_out;

    const int B  = in_sizes[0];
    const int na = in_sizes[1];
    const int nd = in_sizes[3];
    const int ng = in_sizes[5];

    const int threads = 256;
    const int seg_blocks = (B * 16 + threads - 1) / threads;

    // ca -> out[4B..5B), cd -> out[5B..6B), cg -> out[6B..7B)
    seg_mean_kernel<<<seg_blocks, threads, 0, stream>>>(a_idx,  a_seg,  na, user_id, ufac, efac, out + (size_t)4 * B, B);
    seg_mean_kernel<<<seg_blocks, threads, 0, stream>>>(dd_idx, dd_seg, nd, user_id, ufac, efac, out + (size_t)5 * B, B);
    seg_mean_kernel<<<seg_blocks, threads, 0, stream>>>(g_idx,  g_seg,  ng, user_id, ufac, efac, out + (size_t)6 * B, B);

    finalize_kernel<<<(B + threads - 1) / threads, threads, 0, stream>>>(user_id, ufac, relk, out, B);
}

// Round 2
// 55.214 us; speedup vs baseline: 1.7476x; 1.7476x over previous
//
#include <hip/hip_runtime.h>
#include <hip/hip_bf16.h>

// ---------------------------------------------------------------------------
// Phase 0 (prep): segment-boundary detection for all three ragged arrays +
// gather user rows U[b] = ufac[user_id[b]] into workspace.
// Thread space: [0, na+nd+ng) -> boundaries; [ntot, ntot+B*16) -> user gather.
// ---------------------------------------------------------------------------
__global__ void prep_kernel(const int* __restrict__ a_seg, int na, int* __restrict__ st_a,
                            const int* __restrict__ d_seg, int nd, int* __restrict__ st_d,
                            const int* __restrict__ g_seg, int ng, int* __restrict__ st_g,
                            const int* __restrict__ user_id,
                            const float* __restrict__ ufac,
                            float* __restrict__ U,
                            int B)
{
    const int ntot = na + nd + ng;
    int t = blockIdx.x * blockDim.x + threadIdx.x;

    if (t < ntot) {
        const int* seg; int* st; int e, n;
        if (t < na)            { seg = a_seg; st = st_a; e = t;            n = na; }
        else if (t < na + nd)  { seg = d_seg; st = st_d; e = t - na;       n = nd; }
        else                   { seg = g_seg; st = st_g; e = t - na - nd;  n = ng; }
        const int s = seg[e];
        if (e == 0 || seg[e - 1] != s) st[s] = e;
        if (e == n - 1) st[B] = n;
        return;
    }
    t -= ntot;
    if (t < B * 16) {
        const int b = t >> 4, lane = t & 15;
        const int uid = user_id[b];
        const float4 v = *reinterpret_cast<const float4*>(ufac + (size_t)uid * 64 + lane * 4);
        *reinterpret_cast<float4*>(U + (size_t)b * 64 + lane * 4) = v;
    }
}

// ---------------------------------------------------------------------------
// Phase 1: element-parallel dot products. One 16-lane group per ragged
// element across all three arrays (concatenated thread space).
// ---------------------------------------------------------------------------
__global__ void dots_kernel(const int* __restrict__ a_idx, const int* __restrict__ a_seg, float* __restrict__ dots_a, int na,
                            const int* __restrict__ d_idx, const int* __restrict__ d_seg, float* __restrict__ dots_d, int nd,
                            const int* __restrict__ g_idx, const int* __restrict__ g_seg, float* __restrict__ dots_g, int ng,
                            const float* __restrict__ U,
                            const float* __restrict__ efac)
{
    const int gid = blockIdx.x * blockDim.x + threadIdx.x;
    const int t = gid >> 4, lane = gid & 15;
    const int ntot = na + nd + ng;
    if (t >= ntot) return;

    const int* idx; const int* seg; float* dots; int e;
    if (t < na)           { idx = a_idx; seg = a_seg; dots = dots_a; e = t; }
    else if (t < na + nd) { idx = d_idx; seg = d_seg; dots = dots_d; e = t - na; }
    else                  { idx = g_idx; seg = g_seg; dots = dots_g; e = t - na - nd; }

    const int s  = seg[e];
    const int ei = idx[e];
    const float4 uv = *reinterpret_cast<const float4*>(U    + (size_t)s  * 64 + lane * 4);
    const float4 ev = *reinterpret_cast<const float4*>(efac + (size_t)ei * 64 + lane * 4);
    float acc = uv.x * ev.x + uv.y * ev.y + uv.z * ev.z + uv.w * ev.w;

    acc += __shfl_xor(acc, 1, 64);
    acc += __shfl_xor(acc, 2, 64);
    acc += __shfl_xor(acc, 4, 64);
    acc += __shfl_xor(acc, 8, 64);

    if (lane == 0) dots[e] = acc;
}

// ---------------------------------------------------------------------------
// Phase 2: segment means. One 16-lane group per (which, b).
// ---------------------------------------------------------------------------
__global__ void segmean_kernel(const float* __restrict__ dots_a, const int* __restrict__ st_a,
                               const float* __restrict__ dots_d, const int* __restrict__ st_d,
                               const float* __restrict__ dots_g, const int* __restrict__ st_g,
                               float* __restrict__ out, int B)
{
    const int gid = blockIdx.x * blockDim.x + threadIdx.x;
    const int t = gid >> 4, lane = gid & 15;
    if (t >= 3 * B) return;
    const int which = t / B;
    const int b = t - which * B;

    const float* dots; const int* st;
    if (which == 0)      { dots = dots_a; st = st_a; }
    else if (which == 1) { dots = dots_d; st = st_d; }
    else                 { dots = dots_g; st = st_g; }

    const int start = st[b], end = st[b + 1];
    float acc = 0.0f;
    for (int e = start + lane; e < end; e += 16) acc += dots[e];

    acc += __shfl_xor(acc, 1, 64);
    acc += __shfl_xor(acc, 2, 64);
    acc += __shfl_xor(acc, 4, 64);
    acc += __shfl_xor(acc, 8, 64);

    if (lane == 0) out[(size_t)(4 + which) * B + b] = acc / (float)(end - start);
}

// ---------------------------------------------------------------------------
// Phase 3: scores = softmax(leaky_relu(U[b] @ K, 0.2)); prediction = weighted
// mean of ca/cd/cg (already written into out by segmean_kernel).
// ---------------------------------------------------------------------------
__global__ void finalize_kernel(const float* __restrict__ U,
                                const float* __restrict__ relk,  // (64,3) row-major
                                float* __restrict__ out, int B)
{
    const int b = blockIdx.x * blockDim.x + threadIdx.x;
    if (b >= B) return;

    const float* u = U + (size_t)b * 64;
    float s0 = 0.f, s1 = 0.f, s2 = 0.f;
#pragma unroll 8
    for (int d = 0; d < 64; ++d) {
        const float uv = u[d];
        s0 += uv * relk[d * 3 + 0];
        s1 += uv * relk[d * 3 + 1];
        s2 += uv * relk[d * 3 + 2];
    }
    s0 = s0 > 0.f ? s0 : 0.2f * s0;
    s1 = s1 > 0.f ? s1 : 0.2f * s1;
    s2 = s2 > 0.f ? s2 : 0.2f * s2;
    const float m = fmaxf(s0, fmaxf(s1, s2));
    const float e0 = expf(s0 - m), e1 = expf(s1 - m), e2 = expf(s2 - m);
    const float inv = 1.0f / (e0 + e1 + e2);
    const float p0 = e0 * inv, p1 = e1 * inv, p2 = e2 * inv;

    const float ca = out[(size_t)4 * B + b];
    const float cd = out[(size_t)5 * B + b];
    const float cg = out[(size_t)6 * B + b];
    const float pred = (ca * p0 + cd * p1 + cg * p2) / (p0 + p1 + p2);

    out[b] = pred;
    out[(size_t)B + 3 * b + 0] = p0;
    out[(size_t)B + 3 * b + 1] = p1;
    out[(size_t)B + 3 * b + 2] = p2;
}

extern "C" void kernel_launch(void* const* d_in, const int* in_sizes, int n_in,
                              void* d_out, int out_size, void* d_ws, size_t ws_size,
                              hipStream_t stream) {
    const int*   user_id = (const int*)  d_in[0];
    const int*   a_idx   = (const int*)  d_in[1];
    const int*   a_seg   = (const int*)  d_in[2];
    const int*   dd_idx  = (const int*)  d_in[3];
    const int*   dd_seg  = (const int*)  d_in[4];
    const int*   g_idx   = (const int*)  d_in[5];
    const int*   g_seg   = (const int*)  d_in[6];
    const float* ufac    = (const float*)d_in[7];
    const float* efac    = (const float*)d_in[8];
    const float* relk    = (const float*)d_in[9];
    float* out = (float*)d_out;

    const int B  = in_sizes[0];
    const int na = in_sizes[1];
    const int nd = in_sizes[3];
    const int ng = in_sizes[5];
    const int ntot = na + nd + ng;

    // ---- workspace layout (16B-aligned regions) ----
    auto align16 = [](size_t x) { return (x + 15) & ~(size_t)15; };
    char* ws = (char*)d_ws;
    size_t off = 0;
    float* U      = (float*)(ws + off); off += align16((size_t)B * 64 * sizeof(float));
    float* dots_a = (float*)(ws + off); off += align16((size_t)na * sizeof(float));
    float* dots_d = (float*)(ws + off); off += align16((size_t)nd * sizeof(float));
    float* dots_g = (float*)(ws + off); off += align16((size_t)ng * sizeof(float));
    int*   st_a   = (int*)  (ws + off); off += align16((size_t)(B + 1) * sizeof(int));
    int*   st_d   = (int*)  (ws + off); off += align16((size_t)(B + 1) * sizeof(int));
    int*   st_g   = (int*)  (ws + off); off += align16((size_t)(B + 1) * sizeof(int));

    const int threads = 256;

    const int prep_threads = ntot + B * 16;
    prep_kernel<<<(prep_threads + threads - 1) / threads, threads, 0, stream>>>(
        a_seg, na, st_a, dd_seg, nd, st_d, g_seg, ng, st_g, user_id, ufac, U, B);

    const long dots_threads = (long)ntot * 16;
    dots_kernel<<<(dots_threads + threads - 1) / threads, threads, 0, stream>>>(
        a_idx, a_seg, dots_a, na, dd_idx, dd_seg, dots_d, nd, g_idx, g_seg, dots_g, ng, U, efac);

    const int sm_threads = 3 * B * 16;
    segmean_kernel<<<(sm_threads + threads - 1) / threads, threads, 0, stream>>>(
        dots_a, st_a, dots_d, st_d, dots_g, st_g, out, B);

    finalize_kernel<<<(B + threads - 1) / threads, threads, 0, stream>>>(U, relk, out, B);
}